// Round 3
// baseline (746.713 us; speedup 1.0000x reference)
//
#include <hip/hip_runtime.h>

// EHD layer: 3x3 x 8-orientation conv -> argmax+threshold -> 9-bin one-hot
// -> 5x5 box count / 25.  Fused single kernel, u64-packed 9x7-bit histograms.
// R2: vectorized LDS (b128 conv taps, b128 one-hot, sliding hsum).

#define BN   16
#define HH   1024
#define WW   1024
#define NOR  8
#define H2   1018   // output H (1024-2-4)
#define W2   1018   // output W
#define TH   16     // output tile rows
#define TW   64     // output tile cols
#define XH   (TH+6) // 22 staged rows
#define XWS  72     // staged cols, padded to multiple of 4 (valid taps need 0..69)
#define OHH  (TH+4) // 20 one-hot rows
#define OHW  68     // one-hot cols (taps for rs cols 0..63 need oh cols 0..67)

__global__ __launch_bounds__(256)
void ehd_kernel(const float* __restrict__ x,
                const float* __restrict__ masks,
                float* __restrict__ out)
{
    __shared__ __align__(16) float xs[XH][XWS];                 // 6336 B
    __shared__ __align__(16) unsigned long long oh[OHH][OHW];   // 10880 B
    __shared__ __align__(16) unsigned long long rs[OHH][TW];    // 10240 B

    const int tid = threadIdx.x;
    const int w0  = blockIdx.x * TW;
    const int h0  = blockIdx.y * TH;
    const int b   = blockIdx.z;

    // masks (uniform; expected to scalarize)
    float m[NOR][9];
#pragma unroll
    for (int o = 0; o < NOR; ++o)
#pragma unroll
        for (int t = 0; t < 9; ++t)
            m[o][t] = masks[o * 9 + t];

    // ---- stage x tile (edge-clamped; clamped values only feed discarded outputs)
    const float* xb = x + (long)b * HH * WW;
    for (int t = tid; t < XH * XWS; t += 256) {
        int i = t / XWS, j = t - i * XWS;
        int gh = h0 + i; if (gh > HH - 1) gh = HH - 1;
        int gw = w0 + j; if (gw > WW - 1) gw = WW - 1;
        xs[i][j] = xb[gh * WW + gw];
    }
    __syncthreads();

    // ---- conv -> argmax -> threshold -> packed one-hot; 4 pixels/thread
    for (int t = tid; t < OHH * 17; t += 256) {
        int i = t / 17, g = t - i * 17;
        int j0 = g * 4;                       // pixel cols j0..j0+3 (j0<=64)
        const float4 a0 = *(const float4*)&xs[i    ][j0];
        const float4 b0 = *(const float4*)&xs[i    ][j0 + 4];
        const float4 a1 = *(const float4*)&xs[i + 1][j0];
        const float4 b1 = *(const float4*)&xs[i + 1][j0 + 4];
        const float4 a2 = *(const float4*)&xs[i + 2][j0];
        const float4 b2 = *(const float4*)&xs[i + 2][j0 + 4];
        const float r0[6] = {a0.x, a0.y, a0.z, a0.w, b0.x, b0.y};
        const float r1[6] = {a1.x, a1.y, a1.z, a1.w, b1.x, b1.y};
        const float r2[6] = {a2.x, a2.y, a2.z, a2.w, b2.x, b2.y};
        unsigned long long pk[4];
#pragma unroll
        for (int p = 0; p < 4; ++p) {
            const float xv[9] = {r0[p], r0[p + 1], r0[p + 2],
                                 r1[p], r1[p + 1], r1[p + 2],
                                 r2[p], r2[p + 1], r2[p + 2]};
            float best = 0.0f; int bi = 0;
#pragma unroll
            for (int o = 0; o < NOR; ++o) {
                float acc = xv[0] * m[o][0];
#pragma unroll
                for (int k = 1; k < 9; ++k)
                    acc = fmaf(xv[k], m[o][k], acc);   // same order as passing R2 -> bit-identical
                if (o == 0)          { best = acc; bi = 0; }
                else if (acc > best) { best = acc; bi = o; }
            }
            if (best < 0.9f) bi = NOR;
            pk[p] = 1ull << (7 * bi);
        }
        ulonglong2 v0; v0.x = pk[0]; v0.y = pk[1];
        ulonglong2 v1; v1.x = pk[2]; v1.y = pk[3];
        *(ulonglong2*)&oh[i][j0]     = v0;
        *(ulonglong2*)&oh[i][j0 + 2] = v1;
    }
    __syncthreads();

    // ---- horizontal 5-window sums; 4 outputs/thread, sliding add/sub
    for (int t = tid; t < OHH * 16; t += 256) {
        int i = t >> 4, g = t & 15;
        int j0 = g * 4;                       // rs cols j0..j0+3, reads oh[j0..j0+7]
        const ulonglong2 q0 = *(const ulonglong2*)&oh[i][j0];
        const ulonglong2 q1 = *(const ulonglong2*)&oh[i][j0 + 2];
        const ulonglong2 q2 = *(const ulonglong2*)&oh[i][j0 + 4];
        const ulonglong2 q3 = *(const ulonglong2*)&oh[i][j0 + 6];
        unsigned long long c0 = q0.x + q0.y + q1.x + q1.y + q2.x;
        unsigned long long c1 = c0 + q2.y - q0.x;   // packed subtract: fields never underflow
        unsigned long long c2 = c1 + q3.x - q0.y;
        unsigned long long c3 = c2 + q3.y - q1.x;
        ulonglong2 w0v; w0v.x = c0; w0v.y = c1;
        ulonglong2 w1v; w1v.x = c2; w1v.y = c3;
        *(ulonglong2*)&rs[i][j0]     = w0v;
        *(ulonglong2*)&rs[i][j0 + 2] = w1v;
    }
    __syncthreads();

    // ---- vertical 5-window sums, extract 9 bins, coalesced dword stores
    const int j  = tid & 63;
    const int i0 = tid >> 6;
    const int gw = w0 + j;
    for (int ii = i0; ii < TH; ii += 4) {
        const int gh = h0 + ii;
        unsigned long long s = rs[ii][j];
#pragma unroll
        for (int d = 1; d < 5; ++d) s += rs[ii + d][j];
        if (gh < H2 && gw < W2) {
#pragma unroll
            for (int k = 0; k < 9; ++k) {
                float c = (float)((unsigned)(s >> (7 * k)) & 0x7Fu);
                out[(((long)b * 9 + k) * H2 + gh) * W2 + gw] = c * (1.0f / 25.0f);
            }
        }
    }
}

extern "C" void kernel_launch(void* const* d_in, const int* in_sizes, int n_in,
                              void* d_out, int out_size, void* d_ws, size_t ws_size,
                              hipStream_t stream)
{
    const float* x     = (const float*)d_in[0];
    const float* masks = (const float*)d_in[1];
    float* out         = (float*)d_out;

    dim3 grid((W2 + TW - 1) / TW,   // 16
              (H2 + TH - 1) / TH,   // 64
              BN);                  // 16
    ehd_kernel<<<grid, 256, 0, stream>>>(x, masks, out);
}

// Round 4
// 697.028 us; speedup vs baseline: 1.0713x; 1.0713x over previous
//
#include <hip/hip_runtime.h>

// EHD layer: 3x3 x 8-orientation conv -> argmax+threshold -> 9-bin one-hot
// -> 5x5 box count / 25.
// R3: full-width row-stripe blocks. Each block owns 1018 cols x RPB output
// rows; emits whole 4072 B contiguous plane-rows per iteration (HBM write
// granularity fix: 256 B scattered chunks -> 4 KB runs).

#define NOR 8
#define HH  1024
#define WW  1024
#define H2  1018
#define W2  1018
#define RPB 8             // output rows per block
#define NIT (RPB + 4)     // rs-row iterations per block

__global__ __launch_bounds__(256, 3)
void ehd_rows(const float* __restrict__ x,
              const float* __restrict__ masks,
              float* __restrict__ out)
{
    __shared__ unsigned long long ohrow[WW];     // packed one-hot, cols 0..1021 used
    __shared__ unsigned long long rs[5][WW];     // rolling horizontal 5-sums

    const int t  = threadIdx.x;
    const int r0 = blockIdx.x * RPB;
    const int b  = blockIdx.y;
    const float* xb = x + (long)b * HH * WW;

    // masks: thread-uniform -> scalar loads
    float m[NOR][9];
#pragma unroll
    for (int o = 0; o < NOR; ++o)
#pragma unroll
        for (int k = 0; k < 9; ++k)
            m[o][k] = masks[o * 9 + k];

    // per-thread register x-window: rows rr..rr+2 for 4 cols (j = t + 256c)
    float wr[3][4][3];
#pragma unroll
    for (int s = 0; s < 3; ++s)
#pragma unroll
        for (int c = 0; c < 4; ++c) {
            const int j = t + 256 * c;
#pragma unroll
            for (int d = 0; d < 3; ++d) {
                int jj = j + d; if (jj > WW - 1) jj = WW - 1;
                wr[s][c][d] = xb[(r0 + s) * WW + jj];   // r0+2 <= 1018, in range
            }
        }

    int slot = 0;
    for (int rr = 0; rr < NIT; ++rr) {
        // ---- prefetch x row rr+3 (used next iteration)
        float pf[4][3];
        {
            int nr = r0 + rr + 3; if (nr > HH - 1) nr = HH - 1;
#pragma unroll
            for (int c = 0; c < 4; ++c) {
                const int j = t + 256 * c;
#pragma unroll
                for (int d = 0; d < 3; ++d) {
                    int jj = j + d; if (jj > WW - 1) jj = WW - 1;
                    pf[c][d] = xb[nr * WW + jj];
                }
            }
        }

        // ---- phase 1: conv -> argmax -> threshold -> packed one-hot row
#pragma unroll
        for (int c = 0; c < 4; ++c) {
            const int j = t + 256 * c;
            if (j <= WW - 3) {                     // j <= 1021
                const float xv[9] = { wr[0][c][0], wr[0][c][1], wr[0][c][2],
                                      wr[1][c][0], wr[1][c][1], wr[1][c][2],
                                      wr[2][c][0], wr[2][c][1], wr[2][c][2] };
                float best = 0.0f; int bi = 0;
#pragma unroll
                for (int o = 0; o < NOR; ++o) {
                    float acc = xv[0] * m[o][0];
#pragma unroll
                    for (int k = 1; k < 9; ++k)
                        acc = fmaf(xv[k], m[o][k], acc);  // same order as R2 -> bit-identical
                    if (o == 0)          { best = acc; bi = 0; }
                    else if (acc > best) { best = acc; bi = o; }
                }
                if (best < 0.9f) bi = NOR;
                ohrow[j] = 1ull << (7 * bi);
            }
        }
        __syncthreads();

        // ---- phase 2: horizontal 5-window sums into rolling slot
#pragma unroll
        for (int c = 0; c < 4; ++c) {
            const int j = t + 256 * c;
            if (j <= W2 - 1) {                     // j <= 1017
                unsigned long long s = ohrow[j] + ohrow[j + 1] + ohrow[j + 2]
                                     + ohrow[j + 3] + ohrow[j + 4];
                rs[slot][j] = s;
            }
        }

        // ---- emit output row ro = r0+rr-4 (reads only this thread's rs cols)
        if (rr >= 4) {
            const int ro = r0 + rr - 4;
            if (ro < H2) {
#pragma unroll
                for (int c = 0; c < 4; ++c) {
                    const int j = t + 256 * c;
                    if (j <= W2 - 1) {
                        unsigned long long s = rs[0][j] + rs[1][j] + rs[2][j]
                                             + rs[3][j] + rs[4][j];
#pragma unroll
                        for (int k = 0; k < 9; ++k) {
                            float cv = (float)((unsigned)(s >> (7 * k)) & 0x7Fu) * (1.0f / 25.0f);
                            out[(((long)b * 9 + k) * H2 + ro) * W2 + j] = cv;
                        }
                    }
                }
            }
        }
        __syncthreads();   // protect ohrow before next overwrite

        // ---- rotate register window
#pragma unroll
        for (int c = 0; c < 4; ++c)
#pragma unroll
            for (int d = 0; d < 3; ++d) {
                wr[0][c][d] = wr[1][c][d];
                wr[1][c][d] = wr[2][c][d];
                wr[2][c][d] = pf[c][d];
            }
        slot = (slot == 4) ? 0 : slot + 1;
    }
}

extern "C" void kernel_launch(void* const* d_in, const int* in_sizes, int n_in,
                              void* d_out, int out_size, void* d_ws, size_t ws_size,
                              hipStream_t stream)
{
    const float* x     = (const float*)d_in[0];
    const float* masks = (const float*)d_in[1];
    float* out         = (float*)d_out;

    dim3 grid((H2 + RPB - 1) / RPB,   // 128 row stripes
              16);                    // batch
    ehd_rows<<<grid, 256, 0, stream>>>(x, masks, out);
}